// Round 1
// baseline (1225.033 us; speedup 1.0000x reference)
//
#include <hip/hip_runtime.h>
#include <math.h>

typedef __bf16 bf16;
typedef bf16 bf16x4 __attribute__((ext_vector_type(4)));
typedef bf16 bf16x8 __attribute__((ext_vector_type(8)));
typedef float f32x4 __attribute__((ext_vector_type(4)));

#define NTOK 8192      // B*T
#define CDIM 1024
#define EXP 8
#define DFF 4096
#define BM 128
#define BN 128
#define BK 32

__device__ __forceinline__ void gld_lds16(const bf16* g, bf16* l) {
  __builtin_amdgcn_global_load_lds(
      (const __attribute__((address_space(1))) unsigned int*)g,
      (__attribute__((address_space(3))) unsigned int*)l, 16, 0, 0);
}

// ---------------- transpose + fp32->bf16 convert ----------------
// in: per-expert [R][Cin] fp32, out: per-expert [Cin][R] bf16
__global__ __launch_bounds__(256) void transpose_cvt(
    const float* __restrict__ in, bf16* __restrict__ out, int R, int Cin) {
  __shared__ float tile[32][33];
  int e = blockIdx.z;
  const float* ip = in + (size_t)e * R * Cin;
  bf16* op = out + (size_t)e * R * Cin;
  int c0 = blockIdx.x * 32, r0 = blockIdx.y * 32;
  int tx = threadIdx.x & 31, ty = threadIdx.x >> 5;  // ty in 0..7
#pragma unroll
  for (int i = 0; i < 4; i++)
    tile[ty + 8 * i][tx] = ip[(size_t)(r0 + ty + 8 * i) * Cin + c0 + tx];
  __syncthreads();
#pragma unroll
  for (int i = 0; i < 4; i++)
    op[(size_t)(c0 + ty + 8 * i) * R + r0 + tx] = (bf16)tile[tx][ty + 8 * i];
}

// ---------------- router: logits -> softmax -> top2 -> lists ----------------
__global__ __launch_bounds__(256) void router_kernel(
    const float* __restrict__ x, const float* __restrict__ rw,
    const float* __restrict__ rb, unsigned int* __restrict__ cnt,
    int* __restrict__ list, float* __restrict__ wq) {
  int wave = threadIdx.x >> 6, lane = threadIdx.x & 63;
  int t = blockIdx.x * 4 + wave;
  if (t >= NTOK) return;
  const float* xr = x + (size_t)t * CDIM;
  float acc[8] = {0.f, 0.f, 0.f, 0.f, 0.f, 0.f, 0.f, 0.f};
  for (int c = lane; c < CDIM; c += 64) {
    float xv = xr[c];
    const float4* rp = (const float4*)(rw + c * 8);
    float4 r0 = rp[0], r1 = rp[1];
    acc[0] += xv * r0.x; acc[1] += xv * r0.y;
    acc[2] += xv * r0.z; acc[3] += xv * r0.w;
    acc[4] += xv * r1.x; acc[5] += xv * r1.y;
    acc[6] += xv * r1.z; acc[7] += xv * r1.w;
  }
#pragma unroll
  for (int e = 0; e < 8; e++)
#pragma unroll
    for (int off = 32; off; off >>= 1) acc[e] += __shfl_down(acc[e], off);
  if (lane == 0) {
    float p[8], mx = -1e30f;
#pragma unroll
    for (int e = 0; e < 8; e++) { p[e] = acc[e] + rb[e]; mx = fmaxf(mx, p[e]); }
    float s = 0.f;
#pragma unroll
    for (int e = 0; e < 8; e++) { p[e] = expf(p[e] - mx); s += p[e]; }
    float inv = 1.0f / s;
#pragma unroll
    for (int e = 0; e < 8; e++) p[e] *= inv;
    int i1 = 0;
#pragma unroll
    for (int e = 1; e < 8; e++) if (p[e] > p[i1]) i1 = e;
    int i2 = (i1 == 0) ? 1 : 0;
#pragma unroll
    for (int e = 0; e < 8; e++) if (e != i1 && p[e] > p[i2]) i2 = e;
    unsigned s0 = atomicAdd(&cnt[i1], 1u);
    list[i1 * NTOK + s0] = t * 2;
    unsigned s1 = atomicAdd(&cnt[i2], 1u);
    list[i2 * NTOK + s1] = t * 2 + 1;
    wq[t * 2] = p[i1];
    wq[t * 2 + 1] = p[i2];
  }
}

// ---------------- GEMM1: h[enc] = gelu(x[t] @ w1[e] + b1[e]) ----------------
// A: gathered fp32 x rows (inline cvt), B: w1b[e] = [DFF][C] bf16 (B^T form)
__global__ __launch_bounds__(256) void gemm1_kernel(
    const float* __restrict__ x, const bf16* __restrict__ w1b,
    const float* __restrict__ b1, const int* __restrict__ list,
    const unsigned int* __restrict__ cnt, bf16* __restrict__ h) {
  int e = blockIdx.z;
  int count = (int)min(cnt[e], (unsigned)NTOK);
  int m0 = blockIdx.y * BM;
  if (m0 >= count) return;
  int n0 = blockIdx.x * BN;

  __shared__ __align__(16) bf16 As[BM][BK];
  __shared__ __align__(16) bf16 Bs[BN][BK];
  __shared__ int Ls[BM];

  int tid = threadIdx.x;
  if (tid < BM) {
    int gi = m0 + tid;
    Ls[tid] = (gi < count) ? list[e * NTOK + gi] : 0;
  }
  __syncthreads();

  // A staging plan: 4 passes, each thread converts 4 fp32 -> 4 bf16
  const float* arow[4];
  int arr[4], acol4[4];
#pragma unroll
  for (int p = 0; p < 4; p++) {
    int idx = p * 256 + tid;
    arr[p] = idx >> 3;
    acol4[p] = (idx & 7) * 4;
    arow[p] = x + (size_t)(Ls[arr[p]] >> 1) * CDIM;
  }
  // B staging: 2 async issues of 16B/lane
  const bf16* brow0 = w1b + (size_t)e * DFF * CDIM +
                      (size_t)(n0 + (tid >> 2)) * CDIM + (tid & 3) * 8;
  const bf16* brow1 = brow0 + (size_t)64 * CDIM;
  bf16* bdst0 = &Bs[tid >> 2][(tid & 3) * 8];
  bf16* bdst1 = &Bs[64 + (tid >> 2)][(tid & 3) * 8];

  f32x4 acc[4][4] = {};
  int wave = tid >> 6, lane = tid & 63;
  int wm = wave & 1, wn = wave >> 1;
  int ln = lane & 15, kq = lane >> 4;

  for (int k0 = 0; k0 < CDIM; k0 += BK) {
    __syncthreads();
    gld_lds16(brow0 + k0, bdst0);
    gld_lds16(brow1 + k0, bdst1);
#pragma unroll
    for (int p = 0; p < 4; p++) {
      float4 v = *(const float4*)(arow[p] + k0 + acol4[p]);
      bf16x4 bv;
      bv[0] = (bf16)v.x; bv[1] = (bf16)v.y; bv[2] = (bf16)v.z; bv[3] = (bf16)v.w;
      *(bf16x4*)&As[arr[p]][acol4[p]] = bv;
    }
    __syncthreads();
    bf16x8 af[4], bfr[4];
#pragma unroll
    for (int i = 0; i < 4; i++)
      af[i] = *(bf16x8*)&As[wm * 64 + i * 16 + ln][kq * 8];
#pragma unroll
    for (int j = 0; j < 4; j++)
      bfr[j] = *(bf16x8*)&Bs[wn * 64 + j * 16 + ln][kq * 8];
#pragma unroll
    for (int i = 0; i < 4; i++)
#pragma unroll
      for (int j = 0; j < 4; j++)
        acc[i][j] = __builtin_amdgcn_mfma_f32_16x16x32_bf16(af[i], bfr[j],
                                                            acc[i][j], 0, 0, 0);
  }
  // epilogue: bias + exact gelu -> bf16 h
#pragma unroll
  for (int j = 0; j < 4; j++) {
    int n = n0 + wn * 64 + j * 16 + ln;
    float b1v = b1[e * DFF + n];
#pragma unroll
    for (int i = 0; i < 4; i++) {
#pragma unroll
      for (int r = 0; r < 4; r++) {
        int mrow = wm * 64 + i * 16 + kq * 4 + r;
        if (m0 + mrow < count) {
          int enc = Ls[mrow];
          float v = acc[i][j][r] + b1v;
          float g = 0.5f * v * (1.0f + erff(v * 0.70710678118654752f));
          h[(size_t)enc * DFF + n] = (bf16)g;
        }
      }
    }
  }
}

// ------- GEMM2: out[t] += wq[enc] * (h[enc] @ w2[e] + b2[e]) ----------------
// A: h rows (bf16, gathered), B: w2b[e] = [C][DFF] bf16 (B^T form)
__global__ __launch_bounds__(256) void gemm2_kernel(
    const bf16* __restrict__ h, const bf16* __restrict__ w2b,
    const float* __restrict__ b2, const int* __restrict__ list,
    const unsigned int* __restrict__ cnt, const float* __restrict__ wq,
    float* __restrict__ out) {
  int e = blockIdx.z;
  int count = (int)min(cnt[e], (unsigned)NTOK);
  int m0 = blockIdx.y * BM;
  if (m0 >= count) return;
  int n0 = blockIdx.x * BN;

  __shared__ __align__(16) bf16 As[BM][BK];
  __shared__ __align__(16) bf16 Bs[BN][BK];
  __shared__ int Ls[BM];

  int tid = threadIdx.x;
  if (tid < BM) {
    int gi = m0 + tid;
    Ls[tid] = (gi < count) ? list[e * NTOK + gi] : 0;
  }
  __syncthreads();

  const bf16* arow0 = h + (size_t)Ls[tid >> 2] * DFF + (tid & 3) * 8;
  const bf16* arow1 = h + (size_t)Ls[64 + (tid >> 2)] * DFF + (tid & 3) * 8;
  bf16* adst0 = &As[tid >> 2][(tid & 3) * 8];
  bf16* adst1 = &As[64 + (tid >> 2)][(tid & 3) * 8];
  const bf16* brow0 = w2b + (size_t)e * CDIM * DFF +
                      (size_t)(n0 + (tid >> 2)) * DFF + (tid & 3) * 8;
  const bf16* brow1 = brow0 + (size_t)64 * DFF;
  bf16* bdst0 = &Bs[tid >> 2][(tid & 3) * 8];
  bf16* bdst1 = &Bs[64 + (tid >> 2)][(tid & 3) * 8];

  f32x4 acc[4][4] = {};
  int wave = tid >> 6, lane = tid & 63;
  int wm = wave & 1, wn = wave >> 1;
  int ln = lane & 15, kq = lane >> 4;

  for (int k0 = 0; k0 < DFF; k0 += BK) {
    __syncthreads();
    gld_lds16(arow0 + k0, adst0);
    gld_lds16(arow1 + k0, adst1);
    gld_lds16(brow0 + k0, bdst0);
    gld_lds16(brow1 + k0, bdst1);
    __syncthreads();
    bf16x8 af[4], bfr[4];
#pragma unroll
    for (int i = 0; i < 4; i++)
      af[i] = *(bf16x8*)&As[wm * 64 + i * 16 + ln][kq * 8];
#pragma unroll
    for (int j = 0; j < 4; j++)
      bfr[j] = *(bf16x8*)&Bs[wn * 64 + j * 16 + ln][kq * 8];
#pragma unroll
    for (int i = 0; i < 4; i++)
#pragma unroll
      for (int j = 0; j < 4; j++)
        acc[i][j] = __builtin_amdgcn_mfma_f32_16x16x32_bf16(af[i], bfr[j],
                                                            acc[i][j], 0, 0, 0);
  }
#pragma unroll
  for (int j = 0; j < 4; j++) {
    int n = n0 + wn * 64 + j * 16 + ln;
    float b2v = b2[e * CDIM + n];
#pragma unroll
    for (int i = 0; i < 4; i++) {
#pragma unroll
      for (int r = 0; r < 4; r++) {
        int mrow = wm * 64 + i * 16 + kq * 4 + r;
        if (m0 + mrow < count) {
          int enc = Ls[mrow];
          int t = enc >> 1;
          float w = wq[enc];
          atomicAdd(&out[(size_t)t * CDIM + n], w * (acc[i][j][r] + b2v));
        }
      }
    }
  }
}

extern "C" void kernel_launch(void* const* d_in, const int* in_sizes, int n_in,
                              void* d_out, int out_size, void* d_ws,
                              size_t ws_size, hipStream_t stream) {
  const float* x = (const float*)d_in[0];
  const float* rw = (const float*)d_in[1];
  const float* rb = (const float*)d_in[2];
  const float* w1 = (const float*)d_in[3];
  const float* b1 = (const float*)d_in[4];
  const float* w2 = (const float*)d_in[5];
  const float* b2 = (const float*)d_in[6];
  float* out = (float*)d_out;

  // workspace carve (256B aligned)
  char* ws = (char*)d_ws;
  size_t o = 0;
  auto carve = [&](size_t bytes) {
    void* p = ws + o;
    o = (o + bytes + 255) & ~(size_t)255;
    return p;
  };
  bf16* w1b = (bf16*)carve((size_t)EXP * DFF * CDIM * 2);   // 67 MB
  bf16* w2b = (bf16*)carve((size_t)EXP * DFF * CDIM * 2);   // 67 MB
  bf16* h = (bf16*)carve((size_t)2 * NTOK * DFF * 2);       // 134 MB
  int* list = (int*)carve((size_t)EXP * NTOK * 4);
  float* wq = (float*)carve((size_t)2 * NTOK * 4);
  unsigned int* cnt = (unsigned int*)carve(64);

  hipMemsetAsync(out, 0, (size_t)out_size * sizeof(float), stream);
  hipMemsetAsync(cnt, 0, 64, stream);

  // weight transpose+convert: w1 [E][C][DFF] -> [E][DFF][C]; w2 [E][DFF][C] -> [E][C][DFF]
  transpose_cvt<<<dim3(DFF / 32, CDIM / 32, EXP), 256, 0, stream>>>(w1, w1b,
                                                                    CDIM, DFF);
  transpose_cvt<<<dim3(CDIM / 32, DFF / 32, EXP), 256, 0, stream>>>(w2, w2b,
                                                                    DFF, CDIM);
  router_kernel<<<NTOK / 4, 256, 0, stream>>>(x, rw, rb, cnt, list, wq);
  gemm1_kernel<<<dim3(DFF / BN, NTOK / BM, EXP), 256, 0, stream>>>(
      x, w1b, b1, list, cnt, h);
  gemm2_kernel<<<dim3(CDIM / BN, NTOK / BM, EXP), 256, 0, stream>>>(
      h, w2b, b2, list, cnt, wq, out);
}

// Round 2
// 1176.359 us; speedup vs baseline: 1.0414x; 1.0414x over previous
//
#include <hip/hip_runtime.h>
#include <math.h>

typedef __bf16 bf16;
typedef bf16 bf16x4 __attribute__((ext_vector_type(4)));
typedef bf16 bf16x8 __attribute__((ext_vector_type(8)));
typedef float f32x4 __attribute__((ext_vector_type(4)));

#define NTOK 8192      // B*T
#define CDIM 1024
#define EXP 8
#define DFF 4096
#define BM 128
#define BN 128
#define BK 32

__device__ __forceinline__ void gld_lds16(const bf16* g, bf16* l) {
  __builtin_amdgcn_global_load_lds(
      (const __attribute__((address_space(1))) unsigned int*)g,
      (__attribute__((address_space(3))) unsigned int*)l, 16, 0, 0);
}

// ---------------- x fp32 -> bf16 convert (one-shot) ----------------
__global__ __launch_bounds__(256) void convert_x(const float* __restrict__ in,
                                                 bf16* __restrict__ out) {
  int idx = (blockIdx.x * 256 + threadIdx.x) * 8;
  float4 a = *(const float4*)(in + idx);
  float4 b = *(const float4*)(in + idx + 4);
  bf16x8 v;
  v[0] = (bf16)a.x; v[1] = (bf16)a.y; v[2] = (bf16)a.z; v[3] = (bf16)a.w;
  v[4] = (bf16)b.x; v[5] = (bf16)b.y; v[6] = (bf16)b.z; v[7] = (bf16)b.w;
  *(bf16x8*)(out + idx) = v;
}

// ---------------- transpose + fp32->bf16 convert ----------------
// in: per-expert [R][Cin] fp32, out: per-expert [Cin][R] bf16
__global__ __launch_bounds__(256) void transpose_cvt(
    const float* __restrict__ in, bf16* __restrict__ out, int R, int Cin) {
  __shared__ float tile[32][33];
  int e = blockIdx.z;
  const float* ip = in + (size_t)e * R * Cin;
  bf16* op = out + (size_t)e * R * Cin;
  int c0 = blockIdx.x * 32, r0 = blockIdx.y * 32;
  int tx = threadIdx.x & 31, ty = threadIdx.x >> 5;  // ty in 0..7
#pragma unroll
  for (int i = 0; i < 4; i++)
    tile[ty + 8 * i][tx] = ip[(size_t)(r0 + ty + 8 * i) * Cin + c0 + tx];
  __syncthreads();
  // vectorized write: thread handles out-row c, 4 consecutive r
  int c = threadIdx.x >> 3, r4 = (threadIdx.x & 7) * 4;
  bf16x4 v;
  v[0] = (bf16)tile[r4][c];
  v[1] = (bf16)tile[r4 + 1][c];
  v[2] = (bf16)tile[r4 + 2][c];
  v[3] = (bf16)tile[r4 + 3][c];
  *(bf16x4*)&op[(size_t)(c0 + c) * R + r0 + r4] = v;
}

// ---------------- router: logits -> softmax -> top2 -> lists ----------------
__global__ __launch_bounds__(256) void router_kernel(
    const float* __restrict__ x, const float* __restrict__ rw,
    const float* __restrict__ rb, unsigned int* __restrict__ cnt,
    int* __restrict__ list, float* __restrict__ wq) {
  int wave = threadIdx.x >> 6, lane = threadIdx.x & 63;
  int t = blockIdx.x * 4 + wave;
  if (t >= NTOK) return;
  const float* xr = x + (size_t)t * CDIM;
  float acc[8] = {0.f, 0.f, 0.f, 0.f, 0.f, 0.f, 0.f, 0.f};
  for (int c = lane; c < CDIM; c += 64) {
    float xv = xr[c];
    const float4* rp = (const float4*)(rw + c * 8);
    float4 r0 = rp[0], r1 = rp[1];
    acc[0] += xv * r0.x; acc[1] += xv * r0.y;
    acc[2] += xv * r0.z; acc[3] += xv * r0.w;
    acc[4] += xv * r1.x; acc[5] += xv * r1.y;
    acc[6] += xv * r1.z; acc[7] += xv * r1.w;
  }
#pragma unroll
  for (int e = 0; e < 8; e++)
#pragma unroll
    for (int off = 32; off; off >>= 1) acc[e] += __shfl_down(acc[e], off);
  if (lane == 0) {
    float p[8], mx = -1e30f;
#pragma unroll
    for (int e = 0; e < 8; e++) { p[e] = acc[e] + rb[e]; mx = fmaxf(mx, p[e]); }
    float s = 0.f;
#pragma unroll
    for (int e = 0; e < 8; e++) { p[e] = expf(p[e] - mx); s += p[e]; }
    float inv = 1.0f / s;
#pragma unroll
    for (int e = 0; e < 8; e++) p[e] *= inv;
    int i1 = 0;
#pragma unroll
    for (int e = 1; e < 8; e++) if (p[e] > p[i1]) i1 = e;
    int i2 = (i1 == 0) ? 1 : 0;
#pragma unroll
    for (int e = 0; e < 8; e++) if (e != i1 && p[e] > p[i2]) i2 = e;
    unsigned s0 = atomicAdd(&cnt[i1], 1u);
    list[i1 * NTOK + s0] = t * 2;
    unsigned s1 = atomicAdd(&cnt[i2], 1u);
    list[i2 * NTOK + s1] = t * 2 + 1;
    wq[t * 2] = p[i1];
    wq[t * 2 + 1] = p[i2];
  }
}

// ---------------- GEMM1: h[enc] = gelu(xb[t] @ w1[e] + b1[e]) ----------------
// A: gathered bf16 xb rows (async), B: w1b[e] = [DFF][C] bf16 (B^T form)
__global__ __launch_bounds__(256) void gemm1_kernel(
    const bf16* __restrict__ xb, const bf16* __restrict__ w1b,
    const float* __restrict__ b1, const int* __restrict__ list,
    const unsigned int* __restrict__ cnt, bf16* __restrict__ h) {
  int e = blockIdx.z;
  int count = (int)min(cnt[e], (unsigned)NTOK);
  int m0 = blockIdx.y * BM;
  if (m0 >= count) return;
  int n0 = blockIdx.x * BN;

  __shared__ __align__(16) bf16 As[BM][BK];
  __shared__ __align__(16) bf16 Bs[BN][BK];
  __shared__ int Ls[BM];

  int tid = threadIdx.x;
  if (tid < BM) {
    int gi = m0 + tid;
    Ls[tid] = (gi < count) ? list[e * NTOK + gi] : 0;
  }
  __syncthreads();

  const bf16* arow0 = xb + (size_t)(Ls[tid >> 2] >> 1) * CDIM + (tid & 3) * 8;
  const bf16* arow1 =
      xb + (size_t)(Ls[64 + (tid >> 2)] >> 1) * CDIM + (tid & 3) * 8;
  bf16* adst0 = &As[tid >> 2][(tid & 3) * 8];
  bf16* adst1 = &As[64 + (tid >> 2)][(tid & 3) * 8];
  const bf16* brow0 = w1b + (size_t)e * DFF * CDIM +
                      (size_t)(n0 + (tid >> 2)) * CDIM + (tid & 3) * 8;
  const bf16* brow1 = brow0 + (size_t)64 * CDIM;
  bf16* bdst0 = &Bs[tid >> 2][(tid & 3) * 8];
  bf16* bdst1 = &Bs[64 + (tid >> 2)][(tid & 3) * 8];

  f32x4 acc[4][4] = {};
  int wave = tid >> 6, lane = tid & 63;
  int wm = wave & 1, wn = wave >> 1;
  int ln = lane & 15, kq = lane >> 4;

  for (int k0 = 0; k0 < CDIM; k0 += BK) {
    __syncthreads();
    gld_lds16(arow0 + k0, adst0);
    gld_lds16(arow1 + k0, adst1);
    gld_lds16(brow0 + k0, bdst0);
    gld_lds16(brow1 + k0, bdst1);
    __syncthreads();
    bf16x8 af[4], bfr[4];
#pragma unroll
    for (int i = 0; i < 4; i++)
      af[i] = *(bf16x8*)&As[wm * 64 + i * 16 + ln][kq * 8];
#pragma unroll
    for (int j = 0; j < 4; j++)
      bfr[j] = *(bf16x8*)&Bs[wn * 64 + j * 16 + ln][kq * 8];
#pragma unroll
    for (int i = 0; i < 4; i++)
#pragma unroll
      for (int j = 0; j < 4; j++)
        acc[i][j] = __builtin_amdgcn_mfma_f32_16x16x32_bf16(af[i], bfr[j],
                                                            acc[i][j], 0, 0, 0);
  }
  // epilogue: bias + exact gelu -> bf16 h
#pragma unroll
  for (int j = 0; j < 4; j++) {
    int n = n0 + wn * 64 + j * 16 + ln;
    float b1v = b1[e * DFF + n];
#pragma unroll
    for (int i = 0; i < 4; i++) {
#pragma unroll
      for (int r = 0; r < 4; r++) {
        int mrow = wm * 64 + i * 16 + kq * 4 + r;
        if (m0 + mrow < count) {
          int enc = Ls[mrow];
          float v = acc[i][j][r] + b1v;
          float g = 0.5f * v * (1.0f + erff(v * 0.70710678118654752f));
          h[(size_t)enc * DFF + n] = (bf16)g;
        }
      }
    }
  }
}

// ------- GEMM2: out[t] += wq[enc] * (h[enc] @ w2[e] + b2[e]) ----------------
// A: h rows (bf16, gathered), B: w2b[e] = [C][DFF] bf16 (B^T form)
__global__ __launch_bounds__(256) void gemm2_kernel(
    const bf16* __restrict__ h, const bf16* __restrict__ w2b,
    const float* __restrict__ b2, const int* __restrict__ list,
    const unsigned int* __restrict__ cnt, const float* __restrict__ wq,
    float* __restrict__ out) {
  int e = blockIdx.z;
  int count = (int)min(cnt[e], (unsigned)NTOK);
  int m0 = blockIdx.y * BM;
  if (m0 >= count) return;
  int n0 = blockIdx.x * BN;

  __shared__ __align__(16) bf16 As[BM][BK];
  __shared__ __align__(16) bf16 Bs[BN][BK];
  __shared__ int Ls[BM];

  int tid = threadIdx.x;
  if (tid < BM) {
    int gi = m0 + tid;
    Ls[tid] = (gi < count) ? list[e * NTOK + gi] : 0;
  }
  __syncthreads();

  const bf16* arow0 = h + (size_t)Ls[tid >> 2] * DFF + (tid & 3) * 8;
  const bf16* arow1 = h + (size_t)Ls[64 + (tid >> 2)] * DFF + (tid & 3) * 8;
  bf16* adst0 = &As[tid >> 2][(tid & 3) * 8];
  bf16* adst1 = &As[64 + (tid >> 2)][(tid & 3) * 8];
  const bf16* brow0 = w2b + (size_t)e * CDIM * DFF +
                      (size_t)(n0 + (tid >> 2)) * DFF + (tid & 3) * 8;
  const bf16* brow1 = brow0 + (size_t)64 * DFF;
  bf16* bdst0 = &Bs[tid >> 2][(tid & 3) * 8];
  bf16* bdst1 = &Bs[64 + (tid >> 2)][(tid & 3) * 8];

  f32x4 acc[4][4] = {};
  int wave = tid >> 6, lane = tid & 63;
  int wm = wave & 1, wn = wave >> 1;
  int ln = lane & 15, kq = lane >> 4;

  for (int k0 = 0; k0 < DFF; k0 += BK) {
    __syncthreads();
    gld_lds16(arow0 + k0, adst0);
    gld_lds16(arow1 + k0, adst1);
    gld_lds16(brow0 + k0, bdst0);
    gld_lds16(brow1 + k0, bdst1);
    __syncthreads();
    bf16x8 af[4], bfr[4];
#pragma unroll
    for (int i = 0; i < 4; i++)
      af[i] = *(bf16x8*)&As[wm * 64 + i * 16 + ln][kq * 8];
#pragma unroll
    for (int j = 0; j < 4; j++)
      bfr[j] = *(bf16x8*)&Bs[wn * 64 + j * 16 + ln][kq * 8];
#pragma unroll
    for (int i = 0; i < 4; i++)
#pragma unroll
      for (int j = 0; j < 4; j++)
        acc[i][j] = __builtin_amdgcn_mfma_f32_16x16x32_bf16(af[i], bfr[j],
                                                            acc[i][j], 0, 0, 0);
  }
#pragma unroll
  for (int j = 0; j < 4; j++) {
    int n = n0 + wn * 64 + j * 16 + ln;
    float b2v = b2[e * CDIM + n];
#pragma unroll
    for (int i = 0; i < 4; i++) {
#pragma unroll
      for (int r = 0; r < 4; r++) {
        int mrow = wm * 64 + i * 16 + kq * 4 + r;
        if (m0 + mrow < count) {
          int enc = Ls[mrow];
          int t = enc >> 1;
          float w = wq[enc];
          atomicAdd(&out[(size_t)t * CDIM + n], w * (acc[i][j][r] + b2v));
        }
      }
    }
  }
}

extern "C" void kernel_launch(void* const* d_in, const int* in_sizes, int n_in,
                              void* d_out, int out_size, void* d_ws,
                              size_t ws_size, hipStream_t stream) {
  const float* x = (const float*)d_in[0];
  const float* rw = (const float*)d_in[1];
  const float* rb = (const float*)d_in[2];
  const float* w1 = (const float*)d_in[3];
  const float* b1 = (const float*)d_in[4];
  const float* w2 = (const float*)d_in[5];
  const float* b2 = (const float*)d_in[6];
  float* out = (float*)d_out;

  // workspace carve (256B aligned)
  char* ws = (char*)d_ws;
  size_t o = 0;
  auto carve = [&](size_t bytes) {
    void* p = ws + o;
    o = (o + bytes + 255) & ~(size_t)255;
    return p;
  };
  bf16* w1b = (bf16*)carve((size_t)EXP * DFF * CDIM * 2);   // 67 MB
  bf16* w2b = (bf16*)carve((size_t)EXP * DFF * CDIM * 2);   // 67 MB
  bf16* h = (bf16*)carve((size_t)2 * NTOK * DFF * 2);       // 134 MB
  bf16* xb = (bf16*)carve((size_t)NTOK * CDIM * 2);         // 17 MB
  int* list = (int*)carve((size_t)EXP * NTOK * 4);
  float* wq = (float*)carve((size_t)2 * NTOK * 4);
  unsigned int* cnt = (unsigned int*)carve(64);

  hipMemsetAsync(out, 0, (size_t)out_size * sizeof(float), stream);
  hipMemsetAsync(cnt, 0, 64, stream);

  convert_x<<<NTOK * CDIM / (256 * 8), 256, 0, stream>>>(x, xb);
  // weight transpose+convert: w1 [E][C][DFF] -> [E][DFF][C]; w2 [E][DFF][C] -> [E][C][DFF]
  transpose_cvt<<<dim3(DFF / 32, CDIM / 32, EXP), 256, 0, stream>>>(w1, w1b,
                                                                    CDIM, DFF);
  transpose_cvt<<<dim3(CDIM / 32, DFF / 32, EXP), 256, 0, stream>>>(w2, w2b,
                                                                    DFF, CDIM);
  router_kernel<<<NTOK / 4, 256, 0, stream>>>(x, rw, rb, cnt, list, wq);
  gemm1_kernel<<<dim3(DFF / BN, NTOK / BM, EXP), 256, 0, stream>>>(
      xb, w1b, b1, list, cnt, h);
  gemm2_kernel<<<dim3(CDIM / BN, NTOK / BM, EXP), 256, 0, stream>>>(
      h, w2b, b2, list, cnt, wq, out);
}